// Round 3
// baseline (204.909 us; speedup 1.0000x reference)
//
#include <hip/hip_runtime.h>
#include <math.h>

#define NBATCH 32
#define NMASK  3
#define NCLS   80
#define NATTR  85
#define HH     52
#define WW     52
#define NGT    20
#define HW     (HH*WW)            // 2704
#define CPB    (NMASK*HW)         // 8112 cells per batch
#define NTOT   (NBATCH*CPB)       // 259584

// anchors / 416
__constant__ float c_aw9[9] = {10.f/416.f,16.f/416.f,33.f/416.f,30.f/416.f,62.f/416.f,
                               59.f/416.f,116.f/416.f,156.f/416.f,373.f/416.f};
__constant__ float c_ah9[9] = {13.f/416.f,30.f/416.f,23.f/416.f,61.f/416.f,45.f/416.f,
                               119.f/416.f,90.f/416.f,198.f/416.f,326.f/416.f};

// accumulator slots (doubles in d_ws)
// 0 S_obj  1 S_loww  2 S_lowloss  3 corr_num  4 corr_w  5 count
// 6 ciou_num  7 iouw_den  8 objsum  9 recallsum  10 iousum  11 clssum

__device__ __forceinline__ float sigm(float x){ return 1.0f/(1.0f+expf(-x)); }

// base points at attr0 of this cell: inp + ((b*3+a)*85)*HW + (y*W+x)
__device__ __forceinline__ void cell_box(const float* base, int x, int y, int a,
                                         float& px1, float& py1, float& px2, float& py2){
    float tx = base[0*HW], ty = base[1*HW], tw = base[2*HW], th = base[3*HW];
    float sx = sigm(tx), sy = sigm(ty);
    float cx = (sx + (float)x) / (float)WW;
    float cy = (sy + (float)y) / (float)HH;
    float bw = expf(tw) * c_aw9[a];
    float bh = expf(th) * c_ah9[a];
    px1 = cx - bw*0.5f; py1 = cy - bh*0.5f;
    px2 = px1 + bw;     py2 = py1 + bh;
}

__device__ __forceinline__ int best_anchor(float gw, float gh){
    float best = -1.f; int bn = 0;
    #pragma unroll
    for (int n = 0; n < 9; n++){
        float inter = fminf(gw, c_aw9[n]) * fminf(gh, c_ah9[n]);
        float uni   = gw*gh + c_aw9[n]*c_ah9[n] - inter;
        float r = inter / (uni + 1e-10f);
        if (r > best){ best = r; bn = n; }   // first max wins (strict >)
    }
    return bn;
}

__global__ __launch_bounds__(256)
void yolo_passA(const float* __restrict__ inp, const float* __restrict__ gtb,
                double* __restrict__ acc){
    const int b = blockIdx.y;
    const int i = blockIdx.x*256 + threadIdx.x;
    __shared__ float gx1[NGT], gy1[NGT], gx2[NGT], gy2[NGT], gar[NGT];
    if (threadIdx.x < NGT){
        const float* p = gtb + (b*NGT + threadIdx.x)*4;
        float cx=p[0], cy=p[1], w=p[2], h=p[3];
        float x1 = cx - w*0.5f, y1 = cy - h*0.5f;
        float x2 = x1 + w,      y2 = y1 + h;
        gx1[threadIdx.x]=x1; gy1[threadIdx.x]=y1;
        gx2[threadIdx.x]=x2; gy2[threadIdx.x]=y2;
        gar[threadIdx.x]=(x2-x1)*(y2-y1);            // corner-derived, like reference
    }
    __syncthreads();

    double v_obj = 0.0, v_loww = 0.0, v_lowl = 0.0;
    if (i < CPB){
        int a   = i / HW;
        int rem = i - a*HW;
        int y   = rem / WW;
        int x   = rem - y*WW;
        const float* base = inp + ((size_t)(b*NMASK + a)*NATTR)*HW + rem;
        float px1,py1,px2,py2;
        cell_box(base, x, y, a, px1,py1,px2,py2);
        float parea = (px2-px1)*(py2-py1);
        float best = 0.f;
        #pragma unroll 4
        for (int t = 0; t < NGT; t++){
            float ltx = fmaxf(gx1[t], px1), lty = fmaxf(gy1[t], py1);
            float rbx = fminf(gx2[t], px2), rby = fminf(gy2[t], py2);
            float iw  = fmaxf(rbx-ltx, 0.f), ih = fmaxf(rby-lty, 0.f);
            float inter = iw*ih;
            float iou = inter / (gar[t] + parea - inter + 1e-10f);
            best = fmaxf(best, iou);
        }
        float obj = sigm(base[4*HW]);
        bool  low = best < 0.5f;
        v_obj  = (double)obj;
        v_loww = low ? 1.0 : 0.0;
        v_lowl = low ? (double)(obj*obj) : 0.0;
    }

    // wave reduce (64 lanes) then cross-wave via LDS, 3 atomics/block
    int lane = threadIdx.x & 63, wv = threadIdx.x >> 6;
    for (int off = 32; off; off >>= 1){
        v_obj  += __shfl_down(v_obj,  off);
        v_loww += __shfl_down(v_loww, off);
        v_lowl += __shfl_down(v_lowl, off);
    }
    __shared__ double sred[3][4];
    if (lane == 0){ sred[0][wv]=v_obj; sred[1][wv]=v_loww; sred[2][wv]=v_lowl; }
    __syncthreads();
    if (threadIdx.x == 0){
        atomicAdd(&acc[0], sred[0][0]+sred[0][1]+sred[0][2]+sred[0][3]);
        atomicAdd(&acc[1], sred[1][0]+sred[1][1]+sred[1][2]+sred[1][3]);
        atomicAdd(&acc[2], sred[2][0]+sred[2][1]+sred[2][2]+sred[2][3]);
    }
}

__global__ __launch_bounds__(256)
void yolo_passC(const float* __restrict__ inp, const float* __restrict__ gtb,
                const int* __restrict__ gtc, double* __restrict__ acc){
    int t = blockIdx.x*256 + threadIdx.x;
    if (t >= NBATCH*NGT) return;
    int b = t / NGT;
    int j = t - b*NGT;

    const float* gp = gtb + t*4;
    float gcx = gp[0], gcy = gp[1], gw = gp[2], gh = gp[3];
    int  bn    = best_anchor(gw, gh);
    bool valid = bn < NMASK;
    int  kk    = valid ? bn : 0;
    int gi = (int)(gcx * (float)WW); gi = min(max(gi,0), WW-1);
    int gj = (int)(gcy * (float)HH); gj = min(max(gj,0), HH-1);
    int rem = gj*WW + gi;
    const float* base = inp + ((size_t)(b*NMASK + kk)*NATTR)*HW + rem;

    float px1,py1,px2,py2;
    cell_box(base, gi, gj, kk, px1,py1,px2,py2);
    float conf = sigm(base[4*HW]);
    int   cls  = gtc[t];
    float clsp = sigm(base[(5+cls)*HW]);

    // gt corners
    float x1 = gcx - gw*0.5f, y1 = gcy - gh*0.5f;
    float x2 = x1 + gw,       y2 = y1 + gh;

    // CIoU (reference _ciou, eps=1e-9)
    const float eps = 1e-9f;
    float ltx = fmaxf(x1, px1), lty = fmaxf(y1, py1);
    float rbx = fminf(x2, px2), rby = fminf(y2, py2);
    float iw  = fmaxf(rbx-ltx, 0.f), ih = fmaxf(rby-lty, 0.f);
    float inter = iw*ih;
    float w1 = x2-x1, h1 = y2-y1;
    float w2 = px2-px1, h2 = py2-py1;
    float uni = w1*h1 + w2*h2 - inter;
    float iou = inter / (uni + eps);
    float cl = fminf(x1,px1), ct = fminf(y1,py1);
    float cr = fmaxf(x2,px2), cb = fmaxf(y2,py2);
    float c2 = (cr-cl)*(cr-cl) + (cb-ct)*(cb-ct) + eps;
    float dx = (x1+x2-px1-px2)*0.5f, dy = (y1+y2-py1-py2)*0.5f;
    float d2 = dx*dx + dy*dy;
    float at1 = atanf(w1/(h1+eps)), at2 = atanf(w2/(h2+eps));
    float v = (4.0f/(float)(M_PI*M_PI)) * (at1-at2)*(at1-at2);
    float alpha = v / (1.f - iou + v + eps);
    float ciou = iou - d2/c2 - alpha*v;

    float area = (x2-x1)*(y2-y1);
    float iouw = 2.f - area;
    float vf = valid ? 1.f : 0.f;

    atomicAdd(&acc[5],  (double)vf);
    atomicAdd(&acc[6],  (double)(vf * (1.f-ciou)*(1.f-ciou) * iouw));
    atomicAdd(&acc[7],  (double)(vf * iouw));
    atomicAdd(&acc[8],  (double)(vf * conf));
    atomicAdd(&acc[9],  (double)(vf * ((iou > 0.5f) ? 1.f : 0.f)));
    atomicAdd(&acc[10], (double)(vf * iou));
    atomicAdd(&acc[11], (double)(vf * clsp));

    if (!valid) return;

    // last-wins dedup: am I the winner for this lin? (same-batch collisions only)
    for (int j2 = j+1; j2 < NGT; j2++){
        const float* q = gtb + (b*NGT + j2)*4;
        int bn2 = best_anchor(q[2], q[3]);
        if (bn2 >= NMASK) continue;
        int qi = (int)(q[0]*(float)WW); qi = min(max(qi,0), WW-1);
        int qj = (int)(q[1]*(float)HH); qj = min(max(qj,0), HH-1);
        if (bn2 == bn && qi == gi && qj == gj) return;  // later entry overwrites
    }

    // scatter correction at this cell: need `low` bit, must bit-match passA
    float parea = (px2-px1)*(py2-py1);
    float best = 0.f;
    for (int u = 0; u < NGT; u++){
        const float* q = gtb + (b*NGT + u)*4;
        float qx1 = q[0]-q[2]*0.5f, qy1 = q[1]-q[3]*0.5f;
        float qx2 = qx1 + q[2],     qy2 = qy1 + q[3];
        float qar = (qx2-qx1)*(qy2-qy1);
        float l2x = fmaxf(qx1, px1), l2y = fmaxf(qy1, py1);
        float r2x = fminf(qx2, px2), r2y = fminf(qy2, py2);
        float w_  = fmaxf(r2x-l2x, 0.f), h_ = fmaxf(r2y-l2y, 0.f);
        float in2 = w_*h_;
        float iou2 = in2 / (qar + parea - in2 + 1e-10f);
        best = fmaxf(best, iou2);
    }
    bool low = best < 0.5f;

    float csum = 0.f;
    for (int c = 0; c < NCLS; c++){
        float oc = sigm(base[(5+c)*HW]);
        float tc = (c == cls) ? 0.90125f : 0.00125f;   // one_hot*0.9 + 0.1/80
        float d  = oc - tc;
        csum += d*d;
    }
    float dnum = (conf-1.f)*(conf-1.f) + csum - (low ? conf*conf : 0.f);
    float dw   = 81.f - (low ? 1.f : 0.f);
    atomicAdd(&acc[3], (double)dnum);
    atomicAdd(&acc[4], (double)dw);
}

__global__ void yolo_passD(const double* __restrict__ acc, float* __restrict__ out){
    if (threadIdx.x != 0 || blockIdx.x != 0) return;
    double loss_main = (acc[2] + acc[3]) / (acc[1] + acc[4]);
    double count = acc[5];
    double cnt   = fmax(count, 1.0);
    double iou_loss = acc[6] / fmax(acc[7], 1e-10) / cnt;
    out[0] = (float)(loss_main + 0.01 * iou_loss);          // loss
    out[1] = (float)(acc[9]  / cnt);                        // recall
    out[2] = (float)(acc[10] / cnt);                        // avg_iou
    out[3] = (float)(acc[8]  / cnt);                        // obj_avg
    out[4] = (float)((acc[0] - acc[8]) / ((double)NTOT - count)); // no_obj
    out[5] = (float)(acc[11] / cnt);                        // cls_avg
    out[6] = (float)(count / (double)NBATCH);               // count/bs
}

extern "C" void kernel_launch(void* const* d_in, const int* in_sizes, int n_in,
                              void* d_out, int out_size, void* d_ws, size_t ws_size,
                              hipStream_t stream) {
    const float* inp = (const float*)d_in[0];
    const float* gtb = (const float*)d_in[1];
    const int*   gtc = (const int*)d_in[2];
    float* out = (float*)d_out;
    double* acc = (double*)d_ws;

    hipMemsetAsync(acc, 0, 12*sizeof(double), stream);

    dim3 gA((CPB + 255)/256, NBATCH);
    yolo_passA<<<gA, 256, 0, stream>>>(inp, gtb, acc);
    yolo_passC<<<(NBATCH*NGT + 255)/256, 256, 0, stream>>>(inp, gtb, gtc, acc);
    yolo_passD<<<1, 64, 0, stream>>>(acc, out);
}

// Round 6
// 181.074 us; speedup vs baseline: 1.1316x; 1.1316x over previous
//
#include <hip/hip_runtime.h>
#include <math.h>

#define NBATCH 32
#define NMASK  3
#define NCLS   80
#define NATTR  85
#define HH     52
#define WW     52
#define NGT    20
#define HW     (HH*WW)            // 2704
#define CPB    (NMASK*HW)         // 8112 cells per batch
#define NTOT   (NBATCH*CPB)       // 259584

#define PA_BPB   32               // blocks per batch for passA (8112/256 -> 32)
#define PA_BLOCKS (PA_BPB*NBATCH) // 1024
#define PC_BLOCKS 160             // 160 blocks * 4 waves = 640 entries
#define NBLK     (PA_BLOCKS + PC_BLOCKS)

// anchors / 416
__constant__ float c_aw9[9] = {10.f/416.f,16.f/416.f,33.f/416.f,30.f/416.f,62.f/416.f,
                               59.f/416.f,116.f/416.f,156.f/416.f,373.f/416.f};
__constant__ float c_ah9[9] = {13.f/416.f,30.f/416.f,23.f/416.f,61.f/416.f,45.f/416.f,
                               119.f/416.f,90.f/416.f,198.f/416.f,326.f/416.f};

// accumulator slots (doubles in d_ws)
// 0 S_obj  1 S_loww  2 S_lowloss  3 corr_num  4 corr_w  5 count
// 6 ciou_num  7 iouw_den  8 objsum  9 recallsum  10 iousum  11 clssum
// [12] : u32 block-completion counter

__device__ __forceinline__ float sigm(float x){ return 1.0f/(1.0f+expf(-x)); }

__device__ __forceinline__ void cell_box(const float* base, int x, int y, int a,
                                         float& px1, float& py1, float& px2, float& py2){
    float tx = base[0*HW], ty = base[1*HW], tw = base[2*HW], th = base[3*HW];
    float sx = sigm(tx), sy = sigm(ty);
    float cx = (sx + (float)x) / (float)WW;
    float cy = (sy + (float)y) / (float)HH;
    float bw = expf(tw) * c_aw9[a];
    float bh = expf(th) * c_ah9[a];
    px1 = cx - bw*0.5f; py1 = cy - bh*0.5f;
    px2 = px1 + bw;     py2 = py1 + bh;
}

__device__ __forceinline__ int best_anchor(float gw, float gh){
    float best = -1.f; int bn = 0;
    #pragma unroll
    for (int n = 0; n < 9; n++){
        float inter = fminf(gw, c_aw9[n]) * fminf(gh, c_ah9[n]);
        float uni   = gw*gh + c_aw9[n]*c_ah9[n] - inter;
        float r = inter / (uni + 1e-10f);
        if (r > best){ best = r; bn = n; }   // first max wins (strict >)
    }
    return bn;
}

__global__ __launch_bounds__(256)
void yolo_main(const float* __restrict__ inp, const float* __restrict__ gtb,
               const int* __restrict__ gtc, double* __restrict__ acc,
               float* __restrict__ out){
    __shared__ float gx1[NGT], gy1[NGT], gx2[NGT], gy2[NGT], gar[NGT];
    __shared__ double sred[3][4];     // passA cross-wave
    __shared__ double cred[9][4];     // passC cross-wave

    const int bi = blockIdx.x;

    if (bi < PA_BLOCKS) {
        // ---------------- pass A: dense per-cell sums ----------------
        const int b = bi / PA_BPB;
        const int i = (bi % PA_BPB)*256 + threadIdx.x;
        if (threadIdx.x < NGT){
            const float* p = gtb + (b*NGT + threadIdx.x)*4;
            float cx=p[0], cy=p[1], w=p[2], h=p[3];
            float x1 = cx - w*0.5f, y1 = cy - h*0.5f;
            float x2 = x1 + w,      y2 = y1 + h;
            gx1[threadIdx.x]=x1; gy1[threadIdx.x]=y1;
            gx2[threadIdx.x]=x2; gy2[threadIdx.x]=y2;
            gar[threadIdx.x]=(x2-x1)*(y2-y1);
        }
        __syncthreads();

        double v_obj = 0.0, v_loww = 0.0, v_lowl = 0.0;
        if (i < CPB){
            int a   = i / HW;
            int rem = i - a*HW;
            int y   = rem / WW;
            int x   = rem - y*WW;
            const float* base = inp + ((size_t)(b*NMASK + a)*NATTR)*HW + rem;
            float px1,py1,px2,py2;
            cell_box(base, x, y, a, px1,py1,px2,py2);
            float parea = (px2-px1)*(py2-py1);
            float best = 0.f;
            #pragma unroll 4
            for (int t = 0; t < NGT; t++){
                float ltx = fmaxf(gx1[t], px1), lty = fmaxf(gy1[t], py1);
                float rbx = fminf(gx2[t], px2), rby = fminf(gy2[t], py2);
                float iw  = fmaxf(rbx-ltx, 0.f), ih = fmaxf(rby-lty, 0.f);
                float inter = iw*ih;
                float iou = inter / (gar[t] + parea - inter + 1e-10f);
                best = fmaxf(best, iou);
            }
            float obj = sigm(base[4*HW]);
            bool  low = best < 0.5f;
            v_obj  = (double)obj;
            v_loww = low ? 1.0 : 0.0;
            v_lowl = low ? (double)(obj*obj) : 0.0;
        }

        int lane = threadIdx.x & 63, wv = threadIdx.x >> 6;
        for (int off = 32; off; off >>= 1){
            v_obj  += __shfl_down(v_obj,  off);
            v_loww += __shfl_down(v_loww, off);
            v_lowl += __shfl_down(v_lowl, off);
        }
        if (lane == 0){ sred[0][wv]=v_obj; sred[1][wv]=v_loww; sred[2][wv]=v_lowl; }
        __syncthreads();
        if (threadIdx.x == 0){
            atomicAdd(&acc[0], sred[0][0]+sred[0][1]+sred[0][2]+sred[0][3]);
            atomicAdd(&acc[1], sred[1][0]+sred[1][1]+sred[1][2]+sred[1][3]);
            atomicAdd(&acc[2], sred[2][0]+sred[2][1]+sred[2][2]+sred[2][3]);
        }
    } else {
        // ---------------- pass C: wave-per-gt-entry gather/scatter ----------------
        const int w    = threadIdx.x >> 6;
        const int lane = threadIdx.x & 63;
        const int t    = (bi - PA_BLOCKS)*4 + w;   // 0..639
        const int b    = t / NGT;
        const int j    = t - b*NGT;

        const float* gp = gtb + t*4;
        float gcx = gp[0], gcy = gp[1], gw = gp[2], gh = gp[3];
        int  bn    = best_anchor(gw, gh);
        bool valid = bn < NMASK;
        int  kk    = valid ? bn : 0;
        int gi = (int)(gcx * (float)WW); gi = min(max(gi,0), WW-1);
        int gj = (int)(gcy * (float)HH); gj = min(max(gj,0), HH-1);
        int rem = gj*WW + gi;
        const float* base = inp + ((size_t)(b*NMASK + kk)*NATTR)*HW + rem;

        float px1,py1,px2,py2;
        cell_box(base, gi, gj, kk, px1,py1,px2,py2);
        float conf = sigm(base[4*HW]);
        int   cls  = gtc[t];
        float clsp = sigm(base[(5+cls)*HW]);

        // gt corners
        float x1 = gcx - gw*0.5f, y1 = gcy - gh*0.5f;
        float x2 = x1 + gw,       y2 = y1 + gh;

        // CIoU (reference _ciou, eps=1e-9) — redundant across lanes
        const float eps = 1e-9f;
        float ltx = fmaxf(x1, px1), lty = fmaxf(y1, py1);
        float rbx = fminf(x2, px2), rby = fminf(y2, py2);
        float iw  = fmaxf(rbx-ltx, 0.f), ih = fmaxf(rby-lty, 0.f);
        float inter = iw*ih;
        float w1 = x2-x1, h1 = y2-y1;
        float w2 = px2-px1, h2 = py2-py1;
        float uni = w1*h1 + w2*h2 - inter;
        float iou = inter / (uni + eps);
        float cl = fminf(x1,px1), ct = fminf(y1,py1);
        float cr = fmaxf(x2,px2), cb = fmaxf(y2,py2);
        float c2 = (cr-cl)*(cr-cl) + (cb-ct)*(cb-ct) + eps;
        float dx = (x1+x2-px1-px2)*0.5f, dy = (y1+y2-py1-py2)*0.5f;
        float d2 = dx*dx + dy*dy;
        float at1 = atanf(w1/(h1+eps)), at2 = atanf(w2/(h2+eps));
        float v = (4.0f/(float)(M_PI*M_PI)) * (at1-at2)*(at1-at2);
        float alpha = v / (1.f - iou + v + eps);
        float ciou = iou - d2/c2 - alpha*v;

        float area = (x2-x1)*(y2-y1);
        float iouw = 2.f - area;
        float vf = valid ? 1.f : 0.f;

        double dnum = 0.0, dw = 0.0;

        if (valid) {
            // last-wins dedup, lane-parallel over later entries of same batch
            bool collide = false;
            int j2 = j + 1 + lane;
            if (j2 < NGT){
                const float* q = gtb + (b*NGT + j2)*4;
                int bn2 = best_anchor(q[2], q[3]);
                if (bn2 == bn){
                    int qi = (int)(q[0]*(float)WW); qi = min(max(qi,0), WW-1);
                    int qj = (int)(q[1]*(float)HH); qj = min(max(qj,0), HH-1);
                    collide = (qi == gi && qj == gj);
                }
            }
            bool winner = !__any(collide);

            if (winner) {
                // `low` recompute, lane-parallel over the 20 gts (must bit-match passA)
                float parea = (px2-px1)*(py2-py1);
                float best = 0.f;
                if (lane < NGT){
                    const float* q = gtb + (b*NGT + lane)*4;
                    float qx1 = q[0]-q[2]*0.5f, qy1 = q[1]-q[3]*0.5f;
                    float qx2 = qx1 + q[2],     qy2 = qy1 + q[3];
                    float qar = (qx2-qx1)*(qy2-qy1);
                    float l2x = fmaxf(qx1, px1), l2y = fmaxf(qy1, py1);
                    float r2x = fminf(qx2, px2), r2y = fminf(qy2, py2);
                    float w_  = fmaxf(r2x-l2x, 0.f), h_ = fmaxf(r2y-l2y, 0.f);
                    float in2 = w_*h_;
                    best = in2 / (qar + parea - in2 + 1e-10f);
                }
                for (int off = 32; off; off >>= 1)
                    best = fmaxf(best, __shfl_xor(best, off));
                bool low = best < 0.5f;

                // class-row squared error, lane-parallel (c = lane, and 64+lane for lane<16)
                float csum;
                {
                    float oc = sigm(base[(5+lane)*HW]);
                    float tc = (lane == cls) ? 0.90125f : 0.00125f;
                    float d  = oc - tc;
                    csum = d*d;
                }
                if (lane < 16){
                    int c = 64 + lane;
                    float oc = sigm(base[(5+c)*HW]);
                    float tc = (c == cls) ? 0.90125f : 0.00125f;
                    float d  = oc - tc;
                    csum += d*d;
                }
                for (int off = 32; off; off >>= 1)
                    csum += __shfl_xor(csum, off);

                dnum = (double)((conf-1.f)*(conf-1.f) + csum - (low ? conf*conf : 0.f));
                dw   = (double)(81.f - (low ? 1.f : 0.f));
            }
        }

        if (lane == 0){
            cred[0][w] = (double)vf;
            cred[1][w] = (double)(vf * (1.f-ciou)*(1.f-ciou) * iouw);
            cred[2][w] = (double)(vf * iouw);
            cred[3][w] = (double)(vf * conf);
            cred[4][w] = (double)(vf * ((iou > 0.5f) ? 1.f : 0.f));
            cred[5][w] = (double)(vf * iou);
            cred[6][w] = (double)(vf * clsp);
            cred[7][w] = dnum;
            cred[8][w] = dw;
        }
        __syncthreads();
        if (threadIdx.x == 0){
            atomicAdd(&acc[5],  cred[0][0]+cred[0][1]+cred[0][2]+cred[0][3]);
            atomicAdd(&acc[6],  cred[1][0]+cred[1][1]+cred[1][2]+cred[1][3]);
            atomicAdd(&acc[7],  cred[2][0]+cred[2][1]+cred[2][2]+cred[2][3]);
            atomicAdd(&acc[8],  cred[3][0]+cred[3][1]+cred[3][2]+cred[3][3]);
            atomicAdd(&acc[9],  cred[4][0]+cred[4][1]+cred[4][2]+cred[4][3]);
            atomicAdd(&acc[10], cred[5][0]+cred[5][1]+cred[5][2]+cred[5][3]);
            atomicAdd(&acc[11], cred[6][0]+cred[6][1]+cred[6][2]+cred[6][3]);
            atomicAdd(&acc[3],  cred[7][0]+cred[7][1]+cred[7][2]+cred[7][3]);
            atomicAdd(&acc[4],  cred[8][0]+cred[8][1]+cred[8][2]+cred[8][3]);
        }
    }

    // ---------------- last-block finalize (replaces passD launch) ----------------
    if (threadIdx.x == 0){
        __threadfence();
        unsigned* ctr = (unsigned*)(acc + 12);
        unsigned old = atomicAdd(ctr, 1u);
        if (old == (unsigned)(NBLK - 1)){
            double a[12];
            #pragma unroll
            for (int s = 0; s < 12; s++) a[s] = atomicAdd(&acc[s], 0.0); // coherent read
            double loss_main = (a[2] + a[3]) / (a[1] + a[4]);
            double count = a[5];
            double cnt   = fmax(count, 1.0);
            double iou_loss = a[6] / fmax(a[7], 1e-10) / cnt;
            out[0] = (float)(loss_main + 0.01 * iou_loss);
            out[1] = (float)(a[9]  / cnt);
            out[2] = (float)(a[10] / cnt);
            out[3] = (float)(a[8]  / cnt);
            out[4] = (float)((a[0] - a[8]) / ((double)NTOT - count));
            out[5] = (float)(a[11] / cnt);
            out[6] = (float)(count / (double)NBATCH);
        }
    }
}

extern "C" void kernel_launch(void* const* d_in, const int* in_sizes, int n_in,
                              void* d_out, int out_size, void* d_ws, size_t ws_size,
                              hipStream_t stream) {
    const float* inp = (const float*)d_in[0];
    const float* gtb = (const float*)d_in[1];
    const int*   gtc = (const int*)d_in[2];
    float* out = (float*)d_out;
    double* acc = (double*)d_ws;

    hipMemsetAsync(acc, 0, 13*sizeof(double), stream);
    yolo_main<<<NBLK, 256, 0, stream>>>(inp, gtb, gtc, acc, out);
}

// Round 7
// 124.676 us; speedup vs baseline: 1.6435x; 1.4524x over previous
//
#include <hip/hip_runtime.h>
#include <math.h>

#define NBATCH 32
#define NMASK  3
#define NCLS   80
#define NATTR  85
#define HH     52
#define WW     52
#define NGT    20
#define HW     (HH*WW)            // 2704
#define CPB    (NMASK*HW)         // 8112 cells per batch
#define NTOT   (NBATCH*CPB)       // 259584

#define PA_BPB   32               // blocks per batch for passA (8112/256 -> 32)
#define PA_BLOCKS (PA_BPB*NBATCH) // 1024
#define PC_BLOCKS 160             // 160 blocks * 4 waves = 640 entries
#define NBLK     (PA_BLOCKS + PC_BLOCKS)

// d_ws layout (doubles):
//   [3*bi .. 3*bi+2]                 PA block bi partials: S_obj, S_loww, S_lowloss
//   [3*1024 + 9*pc .. +8]            PC block pc partials: vf, ciou_num, iouw_den,
//                                    objsum, recall, iousum, clssum, dnum, dw
#define PC_BASE (3*PA_BLOCKS)

// anchors / 416
__constant__ float c_aw9[9] = {10.f/416.f,16.f/416.f,33.f/416.f,30.f/416.f,62.f/416.f,
                               59.f/416.f,116.f/416.f,156.f/416.f,373.f/416.f};
__constant__ float c_ah9[9] = {13.f/416.f,30.f/416.f,23.f/416.f,61.f/416.f,45.f/416.f,
                               119.f/416.f,90.f/416.f,198.f/416.f,326.f/416.f};

__device__ __forceinline__ float sigm(float x){ return 1.0f/(1.0f+expf(-x)); }

__device__ __forceinline__ void cell_box(const float* base, int x, int y, int a,
                                         float& px1, float& py1, float& px2, float& py2){
    float tx = base[0*HW], ty = base[1*HW], tw = base[2*HW], th = base[3*HW];
    float sx = sigm(tx), sy = sigm(ty);
    float cx = (sx + (float)x) / (float)WW;
    float cy = (sy + (float)y) / (float)HH;
    float bw = expf(tw) * c_aw9[a];
    float bh = expf(th) * c_ah9[a];
    px1 = cx - bw*0.5f; py1 = cy - bh*0.5f;
    px2 = px1 + bw;     py2 = py1 + bh;
}

__device__ __forceinline__ int best_anchor(float gw, float gh){
    float best = -1.f; int bn = 0;
    #pragma unroll
    for (int n = 0; n < 9; n++){
        float inter = fminf(gw, c_aw9[n]) * fminf(gh, c_ah9[n]);
        float uni   = gw*gh + c_aw9[n]*c_ah9[n] - inter;
        float r = inter / (uni + 1e-10f);
        if (r > best){ best = r; bn = n; }   // first max wins (strict >)
    }
    return bn;
}

__global__ __launch_bounds__(256)
void yolo_main(const float* __restrict__ inp, const float* __restrict__ gtb,
               const int* __restrict__ gtc, double* __restrict__ ws){
    __shared__ float gx1[NGT], gy1[NGT], gx2[NGT], gy2[NGT], gar[NGT];
    __shared__ double sred[3][4];     // passA cross-wave
    __shared__ double cred[9][4];     // passC cross-wave

    const int bi = blockIdx.x;

    if (bi < PA_BLOCKS) {
        // ---------------- pass A: dense per-cell sums ----------------
        const int b = bi / PA_BPB;
        const int i = (bi % PA_BPB)*256 + threadIdx.x;
        if (threadIdx.x < NGT){
            const float* p = gtb + (b*NGT + threadIdx.x)*4;
            float cx=p[0], cy=p[1], w=p[2], h=p[3];
            float x1 = cx - w*0.5f, y1 = cy - h*0.5f;
            float x2 = x1 + w,      y2 = y1 + h;
            gx1[threadIdx.x]=x1; gy1[threadIdx.x]=y1;
            gx2[threadIdx.x]=x2; gy2[threadIdx.x]=y2;
            gar[threadIdx.x]=(x2-x1)*(y2-y1);
        }
        __syncthreads();

        double v_obj = 0.0, v_loww = 0.0, v_lowl = 0.0;
        if (i < CPB){
            int a   = i / HW;
            int rem = i - a*HW;
            int y   = rem / WW;
            int x   = rem - y*WW;
            const float* base = inp + ((size_t)(b*NMASK + a)*NATTR)*HW + rem;
            float px1,py1,px2,py2;
            cell_box(base, x, y, a, px1,py1,px2,py2);
            float parea = (px2-px1)*(py2-py1);
            float best = 0.f;
            #pragma unroll 4
            for (int t = 0; t < NGT; t++){
                float ltx = fmaxf(gx1[t], px1), lty = fmaxf(gy1[t], py1);
                float rbx = fminf(gx2[t], px2), rby = fminf(gy2[t], py2);
                float iw  = fmaxf(rbx-ltx, 0.f), ih = fmaxf(rby-lty, 0.f);
                float inter = iw*ih;
                float iou = inter / (gar[t] + parea - inter + 1e-10f);
                best = fmaxf(best, iou);
            }
            float obj = sigm(base[4*HW]);
            bool  low = best < 0.5f;
            v_obj  = (double)obj;
            v_loww = low ? 1.0 : 0.0;
            v_lowl = low ? (double)(obj*obj) : 0.0;
        }

        int lane = threadIdx.x & 63, wv = threadIdx.x >> 6;
        for (int off = 32; off; off >>= 1){
            v_obj  += __shfl_down(v_obj,  off);
            v_loww += __shfl_down(v_loww, off);
            v_lowl += __shfl_down(v_lowl, off);
        }
        if (lane == 0){ sred[0][wv]=v_obj; sred[1][wv]=v_loww; sred[2][wv]=v_lowl; }
        __syncthreads();
        if (threadIdx.x == 0){
            double* slot = ws + 3*bi;       // distinct slot per block: no atomics
            slot[0] = sred[0][0]+sred[0][1]+sred[0][2]+sred[0][3];
            slot[1] = sred[1][0]+sred[1][1]+sred[1][2]+sred[1][3];
            slot[2] = sred[2][0]+sred[2][1]+sred[2][2]+sred[2][3];
        }
    } else {
        // ---------------- pass C: wave-per-gt-entry gather/scatter ----------------
        const int w    = threadIdx.x >> 6;
        const int lane = threadIdx.x & 63;
        const int t    = (bi - PA_BLOCKS)*4 + w;   // 0..639
        const int b    = t / NGT;
        const int j    = t - b*NGT;

        const float* gp = gtb + t*4;
        float gcx = gp[0], gcy = gp[1], gw = gp[2], gh = gp[3];
        int  bn    = best_anchor(gw, gh);
        bool valid = bn < NMASK;
        int  kk    = valid ? bn : 0;
        int gi = (int)(gcx * (float)WW); gi = min(max(gi,0), WW-1);
        int gj = (int)(gcy * (float)HH); gj = min(max(gj,0), HH-1);
        int rem = gj*WW + gi;
        const float* base = inp + ((size_t)(b*NMASK + kk)*NATTR)*HW + rem;

        float px1,py1,px2,py2;
        cell_box(base, gi, gj, kk, px1,py1,px2,py2);
        float conf = sigm(base[4*HW]);
        int   cls  = gtc[t];
        float clsp = sigm(base[(5+cls)*HW]);

        // gt corners
        float x1 = gcx - gw*0.5f, y1 = gcy - gh*0.5f;
        float x2 = x1 + gw,       y2 = y1 + gh;

        // CIoU (reference _ciou, eps=1e-9) — redundant across lanes
        const float eps = 1e-9f;
        float ltx = fmaxf(x1, px1), lty = fmaxf(y1, py1);
        float rbx = fminf(x2, px2), rby = fminf(y2, py2);
        float iw  = fmaxf(rbx-ltx, 0.f), ih = fmaxf(rby-lty, 0.f);
        float inter = iw*ih;
        float w1 = x2-x1, h1 = y2-y1;
        float w2 = px2-px1, h2 = py2-py1;
        float uni = w1*h1 + w2*h2 - inter;
        float iou = inter / (uni + eps);
        float cl = fminf(x1,px1), ct = fminf(y1,py1);
        float cr = fmaxf(x2,px2), cb = fmaxf(y2,py2);
        float c2 = (cr-cl)*(cr-cl) + (cb-ct)*(cb-ct) + eps;
        float dx = (x1+x2-px1-px2)*0.5f, dy = (y1+y2-py1-py2)*0.5f;
        float d2 = dx*dx + dy*dy;
        float at1 = atanf(w1/(h1+eps)), at2 = atanf(w2/(h2+eps));
        float v = (4.0f/(float)(M_PI*M_PI)) * (at1-at2)*(at1-at2);
        float alpha = v / (1.f - iou + v + eps);
        float ciou = iou - d2/c2 - alpha*v;

        float area = (x2-x1)*(y2-y1);
        float iouw = 2.f - area;
        float vf = valid ? 1.f : 0.f;

        double dnum = 0.0, dw = 0.0;

        if (valid) {
            // last-wins dedup, lane-parallel over later entries of same batch
            bool collide = false;
            int j2 = j + 1 + lane;
            if (j2 < NGT){
                const float* q = gtb + (b*NGT + j2)*4;
                int bn2 = best_anchor(q[2], q[3]);
                if (bn2 == bn){
                    int qi = (int)(q[0]*(float)WW); qi = min(max(qi,0), WW-1);
                    int qj = (int)(q[1]*(float)HH); qj = min(max(qj,0), HH-1);
                    collide = (qi == gi && qj == gj);
                }
            }
            bool winner = !__any(collide);

            if (winner) {
                // `low` recompute, lane-parallel over the 20 gts (must bit-match passA)
                float parea = (px2-px1)*(py2-py1);
                float best = 0.f;
                if (lane < NGT){
                    const float* q = gtb + (b*NGT + lane)*4;
                    float qx1 = q[0]-q[2]*0.5f, qy1 = q[1]-q[3]*0.5f;
                    float qx2 = qx1 + q[2],     qy2 = qy1 + q[3];
                    float qar = (qx2-qx1)*(qy2-qy1);
                    float l2x = fmaxf(qx1, px1), l2y = fmaxf(qy1, py1);
                    float r2x = fminf(qx2, px2), r2y = fminf(qy2, py2);
                    float w_  = fmaxf(r2x-l2x, 0.f), h_ = fmaxf(r2y-l2y, 0.f);
                    float in2 = w_*h_;
                    best = in2 / (qar + parea - in2 + 1e-10f);
                }
                for (int off = 32; off; off >>= 1)
                    best = fmaxf(best, __shfl_xor(best, off));
                bool low = best < 0.5f;

                // class-row squared error, lane-parallel (c = lane, and 64+lane for lane<16)
                float csum;
                {
                    float oc = sigm(base[(5+lane)*HW]);
                    float tc = (lane == cls) ? 0.90125f : 0.00125f;
                    float d  = oc - tc;
                    csum = d*d;
                }
                if (lane < 16){
                    int c = 64 + lane;
                    float oc = sigm(base[(5+c)*HW]);
                    float tc = (c == cls) ? 0.90125f : 0.00125f;
                    float d  = oc - tc;
                    csum += d*d;
                }
                for (int off = 32; off; off >>= 1)
                    csum += __shfl_xor(csum, off);

                dnum = (double)((conf-1.f)*(conf-1.f) + csum - (low ? conf*conf : 0.f));
                dw   = (double)(81.f - (low ? 1.f : 0.f));
            }
        }

        if (lane == 0){
            cred[0][w] = (double)vf;
            cred[1][w] = (double)(vf * (1.f-ciou)*(1.f-ciou) * iouw);
            cred[2][w] = (double)(vf * iouw);
            cred[3][w] = (double)(vf * conf);
            cred[4][w] = (double)(vf * ((iou > 0.5f) ? 1.f : 0.f));
            cred[5][w] = (double)(vf * iou);
            cred[6][w] = (double)(vf * clsp);
            cred[7][w] = dnum;
            cred[8][w] = dw;
        }
        __syncthreads();
        if (threadIdx.x == 0){
            double* slot = ws + PC_BASE + 9*(bi - PA_BLOCKS);   // distinct slot
            #pragma unroll
            for (int s = 0; s < 9; s++)
                slot[s] = cred[s][0]+cred[s][1]+cred[s][2]+cred[s][3];
        }
    }
}

__global__ __launch_bounds__(256)
void yolo_reduce(const double* __restrict__ ws, float* __restrict__ out){
    const int tid  = threadIdx.x;
    const int lane = tid & 63;
    const int wv   = tid >> 6;

    double pa0=0.0, pa1=0.0, pa2=0.0;
    for (int i = tid; i < PA_BLOCKS; i += 256){
        const double* s = ws + 3*i;
        pa0 += s[0]; pa1 += s[1]; pa2 += s[2];
    }
    double pc[9] = {0,0,0,0,0,0,0,0,0};
    for (int i = tid; i < PC_BLOCKS; i += 256){
        const double* s = ws + PC_BASE + 9*i;
        #pragma unroll
        for (int k = 0; k < 9; k++) pc[k] += s[k];
    }

    for (int off = 32; off; off >>= 1){
        pa0 += __shfl_down(pa0, off);
        pa1 += __shfl_down(pa1, off);
        pa2 += __shfl_down(pa2, off);
        #pragma unroll
        for (int k = 0; k < 9; k++) pc[k] += __shfl_down(pc[k], off);
    }

    __shared__ double red[12][4];
    if (lane == 0){
        red[0][wv]=pa0; red[1][wv]=pa1; red[2][wv]=pa2;
        #pragma unroll
        for (int k = 0; k < 9; k++) red[3+k][wv] = pc[k];
    }
    __syncthreads();
    if (tid == 0){
        double a[12];
        #pragma unroll
        for (int s = 0; s < 12; s++) a[s] = red[s][0]+red[s][1]+red[s][2]+red[s][3];
        // a0 S_obj, a1 S_loww, a2 S_lowloss
        // a3 count, a4 ciou_num, a5 iouw_den, a6 objsum, a7 recall, a8 iousum,
        // a9 clssum, a10 dnum, a11 dw
        double loss_main = (a[2] + a[10]) / (a[1] + a[11]);
        double count = a[3];
        double cnt   = fmax(count, 1.0);
        double iou_loss = a[4] / fmax(a[5], 1e-10) / cnt;
        out[0] = (float)(loss_main + 0.01 * iou_loss);
        out[1] = (float)(a[7] / cnt);
        out[2] = (float)(a[8] / cnt);
        out[3] = (float)(a[6] / cnt);
        out[4] = (float)((a[0] - a[6]) / ((double)NTOT - count));
        out[5] = (float)(a[9] / cnt);
        out[6] = (float)(count / (double)NBATCH);
    }
}

extern "C" void kernel_launch(void* const* d_in, const int* in_sizes, int n_in,
                              void* d_out, int out_size, void* d_ws, size_t ws_size,
                              hipStream_t stream) {
    const float* inp = (const float*)d_in[0];
    const float* gtb = (const float*)d_in[1];
    const int*   gtc = (const int*)d_in[2];
    float* out = (float*)d_out;
    double* ws = (double*)d_ws;

    yolo_main<<<NBLK, 256, 0, stream>>>(inp, gtb, gtc, ws);
    yolo_reduce<<<1, 256, 0, stream>>>(ws, out);
}